// Round 1
// baseline (410.834 us; speedup 1.0000x reference)
//
#include <hip/hip_runtime.h>
#include <math.h>

// Element-wise physics step, B = 8,388,608 rows, AoS row = 5 floats.
// v2: 4 rows per thread so ALL global traffic is aligned float4 (16 B/lane).
//   x: 5x float4 loads per thread (20 floats = 4 rows)
//   a, noise: 2x float4 loads each
//   out_next: 5x float4 stores; out_reach: 1x float4 store
// Numerics deliberately mirror numpy f32 op-by-op (no FMA contraction in the
// critical chain) so the boolean reached_target boundary matches the ref.

__device__ __forceinline__ void step_one(
    float px0, float py0, float ang0,
    float ax, float ay, float n0, float n1,
    float g0, float g1, float std0, float std1, float gr,
    float& px, float& py, float& ang, float& vel, float& ang_vel, float& reach)
{
    const float DT    = 0.1f;
    const float PI_F  = 3.14159265358979323846f;  // rounds to 3.14159274f
    const float TWOPI = 6.283185307179586f;       // rounds to 6.2831855f

    // vel = g0*a0 + std0*n0 ; ang_vel = g1*a1 + std1*n1  (no fma, numpy order)
    const float w0 = __fmul_rn(std0, n0);
    const float w1 = __fmul_rn(std1, n1);
    vel     = __fadd_rn(__fmul_rn(g0, ax), w0);
    ang_vel = __fadd_rn(__fmul_rn(g1, ay), w1);

    // ang = mod(ang0 + ang_vel*DT + pi, 2pi) - pi  (numpy mod: sign of divisor)
    const float t  = __fadd_rn(ang0, __fmul_rn(ang_vel, DT));
    const float tp = __fadd_rn(t, PI_F);
    float m = fmodf(tp, TWOPI);
    if (m < 0.0f) m = __fadd_rn(m, TWOPI);
    ang = __fsub_rn(m, PI_F);

    float s, c;
    sincosf(ang, &s, &c);  // accurate variant (~2 ulp), matches np closely

    px = __fadd_rn(px0, __fmul_rn(__fmul_rn(vel, c), DT));
    px = fminf(fmaxf(px, -1.0f), 1.0f);
    py = __fadd_rn(py0, __fmul_rn(__fmul_rn(vel, s), DT));
    py = fminf(fmaxf(py, -1.0f), 1.0f);

    const float r2 = __fadd_rn(__fmul_rn(px, px), __fmul_rn(py, py));
    const float r  = __fsqrt_rn(r2);
    reach = (r <= gr) ? 1.0f : 0.0f;
}

__global__ __launch_bounds__(256) void step_kernel(
    const float* __restrict__ x,        // (B,5)
    const float* __restrict__ a,        // (B,2)
    const float* __restrict__ noise,    // (B,2)
    const float* __restrict__ pro_gains,          // (2,)
    const float* __restrict__ pro_noise_ln_vars,  // (2,)
    const float* __restrict__ goal_radius,        // (1,)
    float* __restrict__ out_next,       // (B,5) at d_out
    float* __restrict__ out_reach,      // (B,)  at d_out + 5*B
    int n)
{
    const int nq = n >> 2;  // quads of rows
    const int t = blockIdx.x * blockDim.x + threadIdx.x;

    // Uniform scalars (uniform address -> scalar loads, hoisted).
    const float g0   = pro_gains[0];
    const float g1   = pro_gains[1];
    const float std0 = __fsqrt_rn(expf(pro_noise_ln_vars[0]));
    const float std1 = __fsqrt_rn(expf(pro_noise_ln_vars[1]));
    const float gr   = goal_radius[0];

    if (t < nq) {
        const size_t st = (size_t)t;

        // ---- loads: all aligned float4 ----
        const float4* __restrict__ xq = (const float4*)x;
        const float4 q0 = xq[5 * st + 0];   // f[0..3]
        const float4 q1 = xq[5 * st + 1];   // f[4..7]
        const float4 q2 = xq[5 * st + 2];   // f[8..11]
        const float4 q3 = xq[5 * st + 3];   // f[12..15]
        const float4 q4 = xq[5 * st + 4];   // f[16..19]

        const float4* __restrict__ aq = (const float4*)a;
        const float4 av0 = aq[2 * st + 0];
        const float4 av1 = aq[2 * st + 1];
        const float4* __restrict__ nqv = (const float4*)noise;
        const float4 nv0 = nqv[2 * st + 0];
        const float4 nv1 = nqv[2 * st + 1];

        // row k reads x fields 5k+{0,1,2}
        const float ipx[4]  = { q0.x, q1.y, q2.z, q3.w };
        const float ipy[4]  = { q0.y, q1.z, q2.w, q4.x };
        const float iang[4] = { q0.z, q1.w, q3.x, q4.y };
        const float iax[4]  = { av0.x, av0.z, av1.x, av1.z };
        const float iay[4]  = { av0.y, av0.w, av1.y, av1.w };
        const float in0[4]  = { nv0.x, nv0.z, nv1.x, nv1.z };
        const float in1[4]  = { nv0.y, nv0.w, nv1.y, nv1.w };

        float opx[4], opy[4], oang[4], ovel[4], oavl[4], orch[4];
#pragma unroll
        for (int k = 0; k < 4; ++k) {
            step_one(ipx[k], ipy[k], iang[k], iax[k], iay[k], in0[k], in1[k],
                     g0, g1, std0, std1, gr,
                     opx[k], opy[k], oang[k], ovel[k], oavl[k], orch[k]);
        }

        // ---- stores: all aligned float4 ----
        float4* __restrict__ oq = (float4*)out_next;
        oq[5 * st + 0] = make_float4(opx[0], opy[0], oang[0], ovel[0]);
        oq[5 * st + 1] = make_float4(oavl[0], opx[1], opy[1], oang[1]);
        oq[5 * st + 2] = make_float4(ovel[1], oavl[1], opx[2], opy[2]);
        oq[5 * st + 3] = make_float4(oang[2], ovel[2], oavl[2], opx[3]);
        oq[5 * st + 4] = make_float4(opy[3], oang[3], ovel[3], oavl[3]);
        ((float4*)out_reach)[st] = make_float4(orch[0], orch[1], orch[2], orch[3]);
    }

    // tail rows (n % 4) — scalar path, thread 0 only (never taken for B=8M)
    if ((n & 3) && t == 0) {
        for (int i = nq * 4; i < n; ++i) {
            const size_t si = (size_t)i;
            float px, py, ang, vel, avl, rch;
            step_one(x[5 * si + 0], x[5 * si + 1], x[5 * si + 2],
                     a[2 * si + 0], a[2 * si + 1],
                     noise[2 * si + 0], noise[2 * si + 1],
                     g0, g1, std0, std1, gr, px, py, ang, vel, avl, rch);
            out_next[5 * si + 0] = px;
            out_next[5 * si + 1] = py;
            out_next[5 * si + 2] = ang;
            out_next[5 * si + 3] = vel;
            out_next[5 * si + 4] = avl;
            out_reach[si] = rch;
        }
    }
}

extern "C" void kernel_launch(void* const* d_in, const int* in_sizes, int n_in,
                              void* d_out, int out_size, void* d_ws, size_t ws_size,
                              hipStream_t stream) {
    const float* x       = (const float*)d_in[0];
    const float* a       = (const float*)d_in[1];
    const float* noise   = (const float*)d_in[2];
    const float* gains   = (const float*)d_in[3];
    const float* lnvars  = (const float*)d_in[4];
    const float* gradius = (const float*)d_in[5];

    const int n = in_sizes[0] / 5;            // B
    float* out_next  = (float*)d_out;         // B*5 floats
    float* out_reach = (float*)d_out + (size_t)n * 5;  // B floats

    const int nq = n >> 2;
    const int block = 256;
    int grid = (nq + block - 1) / block;
    if (grid < 1) grid = 1;
    step_kernel<<<grid, block, 0, stream>>>(x, a, noise, gains, lnvars, gradius,
                                            out_next, out_reach, n);
}

// Round 2
// 409.045 us; speedup vs baseline: 1.0044x; 1.0044x over previous
//
#include <hip/hip_runtime.h>
#include <math.h>

// Element-wise physics step, B = 8,388,608 rows.
// v3 = v1 structure (1 row/thread, max TLP — v2's float4 repack regressed) +
// NONTEMPORAL output stores: outputs are write-once/never-read, so keeping
// them out of L2/L3 stops them evicting the 294 MB input set from the
// 256 MB Infinity Cache (rocprof showed FETCH=147MB = half the inputs
// re-missing to HBM every iteration).
// Numerics deliberately mirror numpy f32 op-by-op (no FMA contraction in the
// critical chain) so the boolean reached_target boundary matches the ref.

__global__ __launch_bounds__(256) void step_kernel(
    const float* __restrict__ x,        // (B,5)
    const float* __restrict__ a,        // (B,2)
    const float* __restrict__ noise,    // (B,2)
    const float* __restrict__ pro_gains,          // (2,)
    const float* __restrict__ pro_noise_ln_vars,  // (2,)
    const float* __restrict__ goal_radius,        // (1,)
    float* __restrict__ out_next,       // (B,5) at d_out
    float* __restrict__ out_reach,      // (B,)  at d_out + 5*B
    int n)
{
    int i = blockIdx.x * blockDim.x + threadIdx.x;
    if (i >= n) return;

    // Uniform scalars (uniform address -> scalar loads, hoisted).
    const float g0 = pro_gains[0];
    const float g1 = pro_gains[1];
    const float std0 = __fsqrt_rn(expf(pro_noise_ln_vars[0]));
    const float std1 = __fsqrt_rn(expf(pro_noise_ln_vars[1]));
    const float gr = goal_radius[0];

    const size_t si = (size_t)i;
    const float2 av = *(const float2*)(a + 2 * si);
    const float2 nv = *(const float2*)(noise + 2 * si);
    const float px0  = x[5 * si + 0];
    const float py0  = x[5 * si + 1];
    const float ang0 = x[5 * si + 2];

    // vel = g0*a0 + std0*n0 ; ang_vel = g1*a1 + std1*n1  (no fma, numpy order)
    const float w0 = __fmul_rn(std0, nv.x);
    const float w1 = __fmul_rn(std1, nv.y);
    const float vel     = __fadd_rn(__fmul_rn(g0, av.x), w0);
    const float ang_vel = __fadd_rn(__fmul_rn(g1, av.y), w1);

    const float DT     = 0.1f;
    const float PI_F   = 3.14159265358979323846f;  // rounds to 3.14159274f
    const float TWOPI  = 6.283185307179586f;       // rounds to 6.2831855f

    // ang = mod(ang0 + ang_vel*DT + pi, 2pi) - pi   (numpy mod: sign of divisor)
    const float t  = __fadd_rn(ang0, __fmul_rn(ang_vel, DT));
    const float tp = __fadd_rn(t, PI_F);
    float m = fmodf(tp, TWOPI);
    if (m < 0.0f) m = __fadd_rn(m, TWOPI);
    const float ang = __fsub_rn(m, PI_F);

    float s, c;
    sincosf(ang, &s, &c);  // accurate variant (~2 ulp), matches np closely

    // px = clip(px0 + (vel*cos)*DT, -1, 1) ; same for py with sin
    float px = __fadd_rn(px0, __fmul_rn(__fmul_rn(vel, c), DT));
    px = fminf(fmaxf(px, -1.0f), 1.0f);
    float py = __fadd_rn(py0, __fmul_rn(__fmul_rn(vel, s), DT));
    py = fminf(fmaxf(py, -1.0f), 1.0f);

    // reached = sqrt(px^2 + py^2) <= goal_radius
    const float r2 = __fadd_rn(__fmul_rn(px, px), __fmul_rn(py, py));
    const float r  = __fsqrt_rn(r2);
    const float rch = (r <= gr) ? 1.0f : 0.0f;

    // Nontemporal stores: write-once data, do not allocate in L2/L3.
    __builtin_nontemporal_store(px,      out_next + 5 * si + 0);
    __builtin_nontemporal_store(py,      out_next + 5 * si + 1);
    __builtin_nontemporal_store(ang,     out_next + 5 * si + 2);
    __builtin_nontemporal_store(vel,     out_next + 5 * si + 3);
    __builtin_nontemporal_store(ang_vel, out_next + 5 * si + 4);
    __builtin_nontemporal_store(rch,     out_reach + si);
}

extern "C" void kernel_launch(void* const* d_in, const int* in_sizes, int n_in,
                              void* d_out, int out_size, void* d_ws, size_t ws_size,
                              hipStream_t stream) {
    const float* x      = (const float*)d_in[0];
    const float* a      = (const float*)d_in[1];
    const float* noise  = (const float*)d_in[2];
    const float* gains  = (const float*)d_in[3];
    const float* lnvars = (const float*)d_in[4];
    const float* gradius= (const float*)d_in[5];

    const int n = in_sizes[0] / 5;            // B
    float* out_next  = (float*)d_out;         // B*5 floats
    float* out_reach = (float*)d_out + (size_t)n * 5;  // B floats

    const int block = 256;
    const int grid = (n + block - 1) / block;
    step_kernel<<<grid, block, 0, stream>>>(x, a, noise, gains, lnvars, gradius,
                                            out_next, out_reach, n);
}

// Round 3
// 389.128 us; speedup vs baseline: 1.0558x; 1.0512x over previous
//
#include <hip/hip_runtime.h>
#include <math.h>

// Element-wise physics step, B = 8,388,608 rows, AoS row = 5 floats.
// v4: LDS-staged I/O. Disentangles v1-vs-v2: every GLOBAL access is a
// fully-coalesced dwordx4 (1 KiB/wave/instr) while KEEPING 1 row/thread
// (8M threads, max TLP — the property v2 gave up).
//   stage-in:  x 320xfloat4, a/noise 128xfloat4 each -> LDS
//   compute:   row r = threadIdx.x reads LDS stride-5/stride-2 (conflict-free
//              or 2-way: free per m136)
//   stage-out: out_next 320xfloat4, reach 64xfloat4 from LDS
// LDS 15360 B/block -> 8 blocks/CU possible = 32 waves/CU (not the limiter).
// Numerics identical to v1 (numpy f32 op-by-op, no FMA contraction).

__device__ __forceinline__ void step_one(
    float px0, float py0, float ang0,
    float ax, float ay, float n0, float n1,
    float g0, float g1, float std0, float std1, float gr,
    float& px, float& py, float& ang, float& vel, float& ang_vel, float& reach)
{
    const float DT    = 0.1f;
    const float PI_F  = 3.14159265358979323846f;  // rounds to 3.14159274f
    const float TWOPI = 6.283185307179586f;       // rounds to 6.2831855f

    // vel = g0*a0 + std0*n0 ; ang_vel = g1*a1 + std1*n1  (no fma, numpy order)
    const float w0 = __fmul_rn(std0, n0);
    const float w1 = __fmul_rn(std1, n1);
    vel     = __fadd_rn(__fmul_rn(g0, ax), w0);
    ang_vel = __fadd_rn(__fmul_rn(g1, ay), w1);

    // ang = mod(ang0 + ang_vel*DT + pi, 2pi) - pi  (numpy mod: sign of divisor)
    const float t  = __fadd_rn(ang0, __fmul_rn(ang_vel, DT));
    const float tp = __fadd_rn(t, PI_F);
    float m = fmodf(tp, TWOPI);
    if (m < 0.0f) m = __fadd_rn(m, TWOPI);
    ang = __fsub_rn(m, PI_F);

    float s, c;
    sincosf(ang, &s, &c);  // accurate variant (~2 ulp), matches np closely

    px = __fadd_rn(px0, __fmul_rn(__fmul_rn(vel, c), DT));
    px = fminf(fmaxf(px, -1.0f), 1.0f);
    py = __fadd_rn(py0, __fmul_rn(__fmul_rn(vel, s), DT));
    py = fminf(fmaxf(py, -1.0f), 1.0f);

    const float r2 = __fadd_rn(__fmul_rn(px, px), __fmul_rn(py, py));
    const float r  = __fsqrt_rn(r2);
    reach = (r <= gr) ? 1.0f : 0.0f;
}

__global__ __launch_bounds__(256) void step_kernel(
    const float* __restrict__ x,        // (B,5)
    const float* __restrict__ a,        // (B,2)
    const float* __restrict__ noise,    // (B,2)
    const float* __restrict__ pro_gains,          // (2,)
    const float* __restrict__ pro_noise_ln_vars,  // (2,)
    const float* __restrict__ goal_radius,        // (1,)
    float* __restrict__ out_next,       // (B,5) at d_out
    float* __restrict__ out_reach,      // (B,)  at d_out + 5*B
    int n)
{
    const int t = threadIdx.x;
    const long long rowbase = (long long)blockIdx.x * 256;

    // Uniform scalars (uniform address -> scalar loads, hoisted).
    const float g0   = pro_gains[0];
    const float g1   = pro_gains[1];
    const float std0 = __fsqrt_rn(expf(pro_noise_ln_vars[0]));
    const float std1 = __fsqrt_rn(expf(pro_noise_ln_vars[1]));
    const float gr   = goal_radius[0];

    __shared__ float4 sx4[320];   // 256 rows x 5 floats
    __shared__ float4 sa4[128];   // 256 rows x 2 floats
    __shared__ float4 sn4[128];
    __shared__ float4 so4[320];   // out_next staging
    __shared__ float4 sr4[64];    // reach staging

    if (rowbase + 256 <= (long long)n) {
        // ---- stage-in: fully coalesced float4 ----
        const float4* __restrict__ xg = (const float4*)x + (size_t)blockIdx.x * 320;
        sx4[t] = xg[t];
        if (t < 64) sx4[256 + t] = xg[256 + t];
        const float4* __restrict__ ag = (const float4*)a + (size_t)blockIdx.x * 128;
        const float4* __restrict__ ng = (const float4*)noise + (size_t)blockIdx.x * 128;
        if (t < 128) {
            sa4[t] = ag[t];
            sn4[t] = ng[t];
        }
        __syncthreads();

        // ---- compute: 1 row/thread from LDS ----
        const float* sx = (const float*)sx4;
        const float* sa = (const float*)sa4;
        const float* sn = (const float*)sn4;
        // stride-5 dword reads: gcd(5,32)=1 -> every bank 2 lanes = free.
        const float px0  = sx[5 * t + 0];
        const float py0  = sx[5 * t + 1];
        const float ang0 = sx[5 * t + 2];
        const float ax   = sa[2 * t + 0];
        const float ay   = sa[2 * t + 1];
        const float n0   = sn[2 * t + 0];
        const float n1   = sn[2 * t + 1];

        float px, py, ang, vel, avl, rch;
        step_one(px0, py0, ang0, ax, ay, n0, n1,
                 g0, g1, std0, std1, gr, px, py, ang, vel, avl, rch);

        float* so = (float*)so4;
        so[5 * t + 0] = px;
        so[5 * t + 1] = py;
        so[5 * t + 2] = ang;
        so[5 * t + 3] = vel;
        so[5 * t + 4] = avl;
        ((float*)sr4)[t] = rch;
        __syncthreads();

        // ---- stage-out: fully coalesced float4 ----
        float4* __restrict__ og = (float4*)out_next + (size_t)blockIdx.x * 320;
        og[t] = so4[t];
        if (t < 64) og[256 + t] = so4[256 + t];
        float4* __restrict__ rg = (float4*)out_reach + (size_t)blockIdx.x * 64;
        if (t < 64) rg[t] = sr4[t];
    } else {
        // tail block (n % 256 rows) — v1-style scalar path, guarded
        const long long i = rowbase + t;
        if (i < (long long)n) {
            const size_t si = (size_t)i;
            const float2 av = *(const float2*)(a + 2 * si);
            const float2 nv = *(const float2*)(noise + 2 * si);
            float px, py, ang, vel, avl, rch;
            step_one(x[5 * si + 0], x[5 * si + 1], x[5 * si + 2],
                     av.x, av.y, nv.x, nv.y,
                     g0, g1, std0, std1, gr, px, py, ang, vel, avl, rch);
            out_next[5 * si + 0] = px;
            out_next[5 * si + 1] = py;
            out_next[5 * si + 2] = ang;
            out_next[5 * si + 3] = vel;
            out_next[5 * si + 4] = avl;
            out_reach[si] = rch;
        }
    }
}

extern "C" void kernel_launch(void* const* d_in, const int* in_sizes, int n_in,
                              void* d_out, int out_size, void* d_ws, size_t ws_size,
                              hipStream_t stream) {
    const float* x       = (const float*)d_in[0];
    const float* a       = (const float*)d_in[1];
    const float* noise   = (const float*)d_in[2];
    const float* gains   = (const float*)d_in[3];
    const float* lnvars  = (const float*)d_in[4];
    const float* gradius = (const float*)d_in[5];

    const int n = in_sizes[0] / 5;            // B
    float* out_next  = (float*)d_out;         // B*5 floats
    float* out_reach = (float*)d_out + (size_t)n * 5;  // B floats

    const int block = 256;
    const int grid = (int)(((long long)n + 255) / 256);
    step_kernel<<<grid, block, 0, stream>>>(x, a, noise, gains, lnvars, gradius,
                                            out_next, out_reach, n);
}